// Round 3
// baseline (1770.202 us; speedup 1.0000x reference)
//
#include <hip/hip_runtime.h>

#define H 4
#define C 64
#define D 256
#define NEG_SLOPE 0.2f

// ---------------- tiled GEMM: h[N,256] = x[N,K] @ W[256,K]^T ----------------
template<int K>
__global__ __launch_bounds__(256) void k_gemm(const float* __restrict__ x,
                                              const float* __restrict__ W,
                                              float* __restrict__ h, int nrows) {
    const int KC = 32;
    __shared__ float xs[KC][68];
    __shared__ float ws[KC][68];
    int t  = threadIdx.x;
    int tx = t & 15;      // column group (4 cols each)
    int ty = t >> 4;      // row group (4 rows each)
    int row0 = blockIdx.x * 64;
    int col0 = blockIdx.y * 64;
    float acc[4][4] = {};
    for (int k0 = 0; k0 < K; k0 += KC) {
        #pragma unroll
        for (int n = 0; n < 8; ++n) {
            int idx = n * 256 + t;
            int r = idx >> 5;
            int k = idx & 31;
            int gr = row0 + r;
            float v = 0.f;
            if (gr < nrows) v = x[(size_t)gr * K + k0 + k];
            xs[k][r] = v;
        }
        #pragma unroll
        for (int n = 0; n < 8; ++n) {
            int idx = n * 256 + t;
            int c = idx >> 5;
            int k = idx & 31;
            ws[k][c] = W[(size_t)(col0 + c) * K + k0 + k];
        }
        __syncthreads();
        #pragma unroll
        for (int k = 0; k < KC; ++k) {
            float4 xv = *(const float4*)&xs[k][ty * 4];
            float4 wv = *(const float4*)&ws[k][tx * 4];
            float xa[4] = {xv.x, xv.y, xv.z, xv.w};
            float wa[4] = {wv.x, wv.y, wv.z, wv.w};
            #pragma unroll
            for (int i = 0; i < 4; ++i)
                #pragma unroll
                for (int j = 0; j < 4; ++j)
                    acc[i][j] += xa[i] * wa[j];
        }
        __syncthreads();
    }
    #pragma unroll
    for (int i = 0; i < 4; ++i) {
        int gr = row0 + ty * 4 + i;
        if (gr < nrows) {
            float4 v = make_float4(acc[i][0], acc[i][1], acc[i][2], acc[i][3]);
            *(float4*)&h[(size_t)gr * D + col0 + tx * 4] = v;
        }
    }
}

// ---------------- alpha_src/alpha_dst: wave per (node, head) ----------------
__global__ __launch_bounds__(256) void k_alpha(const float* __restrict__ hmat,
                                               const float* __restrict__ att_src,
                                               const float* __restrict__ att_dst,
                                               float* __restrict__ alpha_src,
                                               float* __restrict__ alpha_dst, int nrows) {
    int node = blockIdx.x;
    if (node >= nrows) return;
    int hh   = threadIdx.x >> 6;   // head = wave id (4 waves)
    int lane = threadIdx.x & 63;   // channel
    float hv = hmat[(size_t)node * D + hh * C + lane];
    float s1 = hv * att_src[hh * C + lane];
    float s2 = hv * att_dst[hh * C + lane];
    #pragma unroll
    for (int off = 32; off > 0; off >>= 1) {
        s1 += __shfl_down(s1, off);
        s2 += __shfl_down(s2, off);
    }
    if (lane == 0) {
        alpha_src[node * H + hh] = s1;
        alpha_dst[node * H + hh] = s2;
    }
}

// ---------------- per-edge: e = exp(leaky_relu(a_s[src]+a_d[dst])), s += e ----------------
__global__ void k_edge(const int* __restrict__ ei, int E, int E2,
                       const float* __restrict__ alpha_src,
                       const float* __restrict__ alpha_dst,
                       float* __restrict__ edge_e,
                       float* __restrict__ s_arr) {
    int e = blockIdx.x * blockDim.x + threadIdx.x;
    if (e >= E2) return;
    int se, de;
    if (e < E) { se = ei[e]; de = ei[E + e]; }
    else       { se = e - E; de = se; }
    #pragma unroll
    for (int hh = 0; hh < H; ++hh) {
        float a = alpha_src[se * H + hh] + alpha_dst[de * H + hh];
        a = a > 0.f ? a : NEG_SLOPE * a;
        float ex = expf(a);
        edge_e[(size_t)e * H + hh] = ex;
        atomicAdd(&s_arr[de * H + hh], ex);
    }
}

// ---------------- CSR build ----------------
__global__ void k_deg(const int* __restrict__ ei, int E, int E2, int* __restrict__ deg) {
    int e = blockIdx.x * blockDim.x + threadIdx.x;
    if (e >= E2) return;
    int de = (e < E) ? ei[E + e] : (e - E);
    atomicAdd(&deg[de], 1);
}

__global__ void k_scan_block(const int* __restrict__ deg, int* __restrict__ incl,
                             int* __restrict__ bsum, int n) {
    __shared__ int sd[256];
    int t = threadIdx.x;
    int i = blockIdx.x * 256 + t;
    int v = (i < n) ? deg[i] : 0;
    sd[t] = v;
    __syncthreads();
    for (int off = 1; off < 256; off <<= 1) {
        int add = (t >= off) ? sd[t - off] : 0;
        __syncthreads();
        sd[t] += add;
        __syncthreads();
    }
    if (i < n) incl[i] = sd[t];
    if (t == 255) bsum[blockIdx.x] = sd[255];
}

__global__ void k_scan_bsum(int* __restrict__ bsum, int nb) {
    __shared__ int sd[256];
    int t = threadIdx.x;
    int v = (t < nb) ? bsum[t] : 0;
    sd[t] = v;
    __syncthreads();
    for (int off = 1; off < 256; off <<= 1) {
        int add = (t >= off) ? sd[t - off] : 0;
        __syncthreads();
        sd[t] += add;
        __syncthreads();
    }
    if (t < nb) bsum[t] = sd[t] - v;  // exclusive block offsets
}

__global__ void k_rowptr(const int* __restrict__ incl, const int* __restrict__ deg,
                         const int* __restrict__ boff, int* __restrict__ row_ptr,
                         int n, int total) {
    int i = blockIdx.x * blockDim.x + threadIdx.x;
    if (i < n) row_ptr[i] = incl[i] - deg[i] + boff[i >> 8];
    if (i == 0) row_ptr[n] = total;
}

__global__ void k_scatter(const int* __restrict__ ei, int E, int E2,
                          const int* __restrict__ row_ptr, int* __restrict__ cursor,
                          int* __restrict__ csr_src, int* __restrict__ csr_eid) {
    int e = blockIdx.x * blockDim.x + threadIdx.x;
    if (e >= E2) return;
    int se, de;
    if (e < E) { se = ei[e]; de = ei[E + e]; }
    else       { se = e - E; de = se; }
    int pos = atomicAdd(&cursor[de], 1);
    int idx = row_ptr[de] + pos;
    csr_src[idx] = se;
    csr_eid[idx] = e;
}

// ---------------- aggregation: out[n] = sum_e (e/s) * h[src_e] + bias ----------------
__global__ __launch_bounds__(256) void k_aggregate(const float* __restrict__ hmat,
        const int* __restrict__ row_ptr, const int* __restrict__ csr_src,
        const int* __restrict__ csr_eid, const float* __restrict__ edge_e,
        const float* __restrict__ s_arr, const float* __restrict__ bias,
        float* __restrict__ out, int relu, int nrows) {
    int node = blockIdx.x;
    if (node >= nrows) return;
    int t  = threadIdx.x;
    int hh = t >> 6;
    int start = row_ptr[node], end = row_ptr[node + 1];
    float sinv = 1.f / (s_arr[node * H + hh] + 1e-16f);
    float acc = 0.f;
    for (int i = start; i < end; ++i) {
        int sn  = csr_src[i];
        int eid = csr_eid[i];
        float a = edge_e[(size_t)eid * H + hh] * sinv;
        acc += a * hmat[(size_t)sn * D + t];
    }
    float v = acc + bias[t];
    if (relu) v = fmaxf(v, 0.f);
    out[(size_t)node * D + t] = v;
}

extern "C" void kernel_launch(void* const* d_in, const int* in_sizes, int n_in,
                              void* d_out, int out_size, void* d_ws, size_t ws_size,
                              hipStream_t stream) {
    const float* x = (const float*)d_in[0];
    const int* ei = (const int*)d_in[1];
    const int N  = in_sizes[0] / 128;   // 50000
    const int E  = in_sizes[1] / 2;     // 400000
    const int E2 = E + N;               // + self loops

    // d_out (N*D f32) doubles as the ping buffer: every layer's aggregate
    // output lands there; the next layer's GEMM reads it; layer 4 leaves
    // the final answer. Fully rewritten every launch -> deterministic.
    float* outbuf = (float*)d_out;

    // -------- workspace carve-up (~64 MB) --------
    char* wsp = (char*)d_ws;
    size_t off = 0;
    auto alloc = [&](size_t bytes) -> void* {
        void* p = wsp + off;
        off += (bytes + 255) & ~(size_t)255;
        return p;
    };
    float* bufH      = (float*)alloc((size_t)N * D * 4);   // GEMM output h
    float* alpha_src = (float*)alloc((size_t)N * H * 4);
    float* alpha_dst = (float*)alloc((size_t)N * H * 4);
    float* s_arr     = (float*)alloc((size_t)N * H * 4);
    float* edge_e    = (float*)alloc((size_t)E2 * H * 4);
    int*   deg       = (int*)alloc((size_t)N * 4);
    int*   incl      = (int*)alloc((size_t)N * 4);
    int*   bsum      = (int*)alloc(256 * 4);
    int*   row_ptr   = (int*)alloc((size_t)(N + 1) * 4);
    int*   cursor    = (int*)alloc((size_t)N * 4);
    int*   csr_src   = (int*)alloc((size_t)E2 * 4);
    int*   csr_eid   = (int*)alloc((size_t)E2 * 4);
    (void)ws_size;

    hipMemsetAsync(deg, 0, (size_t)N * 4, stream);
    hipMemsetAsync(cursor, 0, (size_t)N * 4, stream);

    // ---- build CSR by dst (graph identical across layers) ----
    int egrid = (E2 + 255) / 256;
    k_deg<<<egrid, 256, 0, stream>>>(ei, E, E2, deg);
    int nb = (N + 255) / 256;
    k_scan_block<<<nb, 256, 0, stream>>>(deg, incl, bsum, N);
    k_scan_bsum<<<1, 256, 0, stream>>>(bsum, nb);
    k_rowptr<<<nb, 256, 0, stream>>>(incl, deg, bsum, row_ptr, N, E2);
    k_scatter<<<egrid, 256, 0, stream>>>(ei, E, E2, row_ptr, cursor, csr_src, csr_eid);

    // ---- 5 GAT layers ----
    for (int l = 0; l < 5; ++l) {
        const float* W   = (const float*)d_in[2 + 4 * l];
        const float* as_ = (const float*)d_in[3 + 4 * l];
        const float* ad_ = (const float*)d_in[4 + 4 * l];
        const float* bs_ = (const float*)d_in[5 + 4 * l];

        dim3 gg((N + 63) / 64, D / 64);
        const float* xin = (l == 0) ? x : outbuf;
        if (l == 0) k_gemm<128><<<gg, 256, 0, stream>>>(xin, W, bufH, N);
        else        k_gemm<256><<<gg, 256, 0, stream>>>(xin, W, bufH, N);

        k_alpha<<<N, 256, 0, stream>>>(bufH, as_, ad_, alpha_src, alpha_dst, N);

        hipMemsetAsync(s_arr, 0, (size_t)N * H * 4, stream);
        k_edge<<<egrid, 256, 0, stream>>>(ei, E, E2, alpha_src, alpha_dst, edge_e, s_arr);

        int relu = (l < 4) ? 1 : 0;
        k_aggregate<<<N, 256, 0, stream>>>(bufH, row_ptr, csr_src, csr_eid,
                                           edge_e, s_arr, bs_, outbuf, relu, N);
    }
}

// Round 4
// 952.995 us; speedup vs baseline: 1.8575x; 1.8575x over previous
//
#include <hip/hip_runtime.h>

#define H 4
#define C 64
#define D 256
#define NEG_SLOPE 0.2f

// ---- tiled GEMM: h[N,256] = x[N,K] @ W[256,K]^T, fused alpha epilogue ----
// grid = (ceil(N/64), 4); block col-tile by covers cols by*64..by*64+63 ==
// exactly head `by` (C==64), so this block computes alpha_src/dst[row, by]
// completely (no atomics).
template<int K>
__global__ __launch_bounds__(256) void k_gemm(const float* __restrict__ x,
                                              const float* __restrict__ W,
                                              const float* __restrict__ att_src,
                                              const float* __restrict__ att_dst,
                                              float* __restrict__ h,
                                              float* __restrict__ alpha_src,
                                              float* __restrict__ alpha_dst,
                                              int nrows) {
    const int KC = 32;
    __shared__ float xs[KC][68];
    __shared__ float ws[KC][68];
    int t  = threadIdx.x;
    int tx = t & 15;      // column group (4 cols each)
    int ty = t >> 4;      // row group (4 rows each)
    int row0 = blockIdx.x * 64;
    int col0 = blockIdx.y * 64;
    float acc[4][4] = {};
    for (int k0 = 0; k0 < K; k0 += KC) {
        #pragma unroll
        for (int n = 0; n < 8; ++n) {
            int idx = n * 256 + t;
            int r = idx >> 5;
            int k = idx & 31;
            int gr = row0 + r;
            float v = 0.f;
            if (gr < nrows) v = x[(size_t)gr * K + k0 + k];
            xs[k][r] = v;
        }
        #pragma unroll
        for (int n = 0; n < 8; ++n) {
            int idx = n * 256 + t;
            int c = idx >> 5;
            int k = idx & 31;
            ws[k][c] = W[(size_t)(col0 + c) * K + k0 + k];
        }
        __syncthreads();
        #pragma unroll
        for (int k = 0; k < KC; ++k) {
            float4 xv = *(const float4*)&xs[k][ty * 4];
            float4 wv = *(const float4*)&ws[k][tx * 4];
            float xa[4] = {xv.x, xv.y, xv.z, xv.w};
            float wa[4] = {wv.x, wv.y, wv.z, wv.w};
            #pragma unroll
            for (int i = 0; i < 4; ++i)
                #pragma unroll
                for (int j = 0; j < 4; ++j)
                    acc[i][j] += xa[i] * wa[j];
        }
        __syncthreads();
    }
    // store h tile
    #pragma unroll
    for (int i = 0; i < 4; ++i) {
        int gr = row0 + ty * 4 + i;
        if (gr < nrows) {
            float4 v = make_float4(acc[i][0], acc[i][1], acc[i][2], acc[i][3]);
            *(float4*)&h[(size_t)gr * D + col0 + tx * 4] = v;
        }
    }
    // fused alpha: head = blockIdx.y; channel-within-head = tx*4+j
    float asv[4], adv[4];
    #pragma unroll
    for (int j = 0; j < 4; ++j) {
        asv[j] = att_src[col0 + tx * 4 + j];   // == att_src[by*C + c]
        adv[j] = att_dst[col0 + tx * 4 + j];
    }
    #pragma unroll
    for (int i = 0; i < 4; ++i) {
        float ps = 0.f, pd = 0.f;
        #pragma unroll
        for (int j = 0; j < 4; ++j) {
            ps += acc[i][j] * asv[j];
            pd += acc[i][j] * adv[j];
        }
        // reduce across the 16 tx lanes (lanes with same ty are contiguous)
        #pragma unroll
        for (int m = 1; m < 16; m <<= 1) {
            ps += __shfl_xor(ps, m);
            pd += __shfl_xor(pd, m);
        }
        int gr = row0 + ty * 4 + i;
        if (tx == 0 && gr < nrows) {
            alpha_src[gr * H + blockIdx.y] = ps;
            alpha_dst[gr * H + blockIdx.y] = pd;
        }
    }
}

// ---------------- CSR build (graph constant across layers) ----------------
__global__ void k_deg(const int* __restrict__ ei, int E, int E2, int* __restrict__ deg) {
    int e = blockIdx.x * blockDim.x + threadIdx.x;
    if (e >= E2) return;
    int de = (e < E) ? ei[E + e] : (e - E);
    atomicAdd(&deg[de], 1);
}

__global__ void k_scan_block(const int* __restrict__ deg, int* __restrict__ incl,
                             int* __restrict__ bsum, int n) {
    __shared__ int sd[256];
    int t = threadIdx.x;
    int i = blockIdx.x * 256 + t;
    int v = (i < n) ? deg[i] : 0;
    sd[t] = v;
    __syncthreads();
    for (int off = 1; off < 256; off <<= 1) {
        int add = (t >= off) ? sd[t - off] : 0;
        __syncthreads();
        sd[t] += add;
        __syncthreads();
    }
    if (i < n) incl[i] = sd[t];
    if (t == 255) bsum[blockIdx.x] = sd[255];
}

__global__ void k_scan_bsum(int* __restrict__ bsum, int nb) {
    __shared__ int sd[256];
    int t = threadIdx.x;
    int v = (t < nb) ? bsum[t] : 0;
    sd[t] = v;
    __syncthreads();
    for (int off = 1; off < 256; off <<= 1) {
        int add = (t >= off) ? sd[t - off] : 0;
        __syncthreads();
        sd[t] += add;
        __syncthreads();
    }
    if (t < nb) bsum[t] = sd[t] - v;  // exclusive block offsets
}

__global__ void k_rowptr(const int* __restrict__ incl, const int* __restrict__ deg,
                         const int* __restrict__ boff, int* __restrict__ row_ptr,
                         int n, int total) {
    int i = blockIdx.x * blockDim.x + threadIdx.x;
    if (i < n) row_ptr[i] = incl[i] - deg[i] + boff[i >> 8];
    if (i == 0) row_ptr[n] = total;
}

__global__ void k_scatter(const int* __restrict__ ei, int E, int E2,
                          const int* __restrict__ row_ptr, int* __restrict__ cursor,
                          int* __restrict__ csr_src) {
    int e = blockIdx.x * blockDim.x + threadIdx.x;
    if (e >= E2) return;
    int se, de;
    if (e < E) { se = ei[e]; de = ei[E + e]; }
    else       { se = e - E; de = se; }
    int pos = atomicAdd(&cursor[de], 1);
    csr_src[row_ptr[de] + pos] = se;
}

// ---- aggregation: wave per node; softmax fused (out = Σ e·h / Σe + b) ----
__global__ __launch_bounds__(256) void k_aggregate(const float* __restrict__ hmat,
        const int* __restrict__ row_ptr, const int* __restrict__ csr_src,
        const float* __restrict__ alpha_src, const float* __restrict__ alpha_dst,
        const float* __restrict__ bias, float* __restrict__ out,
        int relu, int nrows) {
    int node = (blockIdx.x * 256 + threadIdx.x) >> 6;   // wave id == node
    if (node >= nrows) return;
    int lane = threadIdx.x & 63;
    int hh   = lane >> 4;         // head (16 lanes per head)
    int c4   = lane * 4;          // 4 consecutive channels per lane
    int start = row_ptr[node], end = row_ptr[node + 1];
    float a_d = alpha_dst[node * H + hh];
    float4 acc = make_float4(0.f, 0.f, 0.f, 0.f);
    float ssum = 0.f;
    int i = start;
    // 8-wide software-pipelined batches: indices -> 8 row loads in flight
    for (; i + 8 <= end; i += 8) {
        int sn[8];
        #pragma unroll
        for (int j = 0; j < 8; ++j) sn[j] = csr_src[i + j];
        float4 hv[8];
        #pragma unroll
        for (int j = 0; j < 8; ++j)
            hv[j] = *(const float4*)&hmat[(size_t)sn[j] * D + c4];
        float as[8];
        #pragma unroll
        for (int j = 0; j < 8; ++j) as[j] = alpha_src[sn[j] * H + hh];
        #pragma unroll
        for (int j = 0; j < 8; ++j) {
            float a = as[j] + a_d;
            a = a > 0.f ? a : NEG_SLOPE * a;
            float ex = __expf(a);
            ssum += ex;
            acc.x += ex * hv[j].x; acc.y += ex * hv[j].y;
            acc.z += ex * hv[j].z; acc.w += ex * hv[j].w;
        }
    }
    for (; i < end; ++i) {
        int sn = csr_src[i];
        float4 hv = *(const float4*)&hmat[(size_t)sn * D + c4];
        float a = alpha_src[sn * H + hh] + a_d;
        a = a > 0.f ? a : NEG_SLOPE * a;
        float ex = __expf(a);
        ssum += ex;
        acc.x += ex * hv.x; acc.y += ex * hv.y; acc.z += ex * hv.z; acc.w += ex * hv.w;
    }
    float sinv = 1.f / (ssum + 1e-16f);
    float4 bv = *(const float4*)&bias[c4];
    float4 o;
    o.x = acc.x * sinv + bv.x;
    o.y = acc.y * sinv + bv.y;
    o.z = acc.z * sinv + bv.z;
    o.w = acc.w * sinv + bv.w;
    if (relu) {
        o.x = fmaxf(o.x, 0.f); o.y = fmaxf(o.y, 0.f);
        o.z = fmaxf(o.z, 0.f); o.w = fmaxf(o.w, 0.f);
    }
    *(float4*)&out[(size_t)node * D + c4] = o;
}

extern "C" void kernel_launch(void* const* d_in, const int* in_sizes, int n_in,
                              void* d_out, int out_size, void* d_ws, size_t ws_size,
                              hipStream_t stream) {
    const float* x = (const float*)d_in[0];
    const int* ei = (const int*)d_in[1];
    const int N  = in_sizes[0] / 128;   // 50000
    const int E  = in_sizes[1] / 2;     // 400000
    const int E2 = E + N;               // + self loops

    float* outbuf = (float*)d_out;      // ping buffer across layers

    char* wsp = (char*)d_ws;
    size_t off = 0;
    auto alloc = [&](size_t bytes) -> void* {
        void* p = wsp + off;
        off += (bytes + 255) & ~(size_t)255;
        return p;
    };
    float* bufH      = (float*)alloc((size_t)N * D * 4);
    float* alpha_src = (float*)alloc((size_t)N * H * 4);
    float* alpha_dst = (float*)alloc((size_t)N * H * 4);
    int*   deg       = (int*)alloc((size_t)N * 4);
    int*   incl      = (int*)alloc((size_t)N * 4);
    int*   bsum      = (int*)alloc(256 * 4);
    int*   row_ptr   = (int*)alloc((size_t)(N + 1) * 4);
    int*   cursor    = (int*)alloc((size_t)N * 4);
    int*   csr_src   = (int*)alloc((size_t)E2 * 4);
    (void)ws_size;

    hipMemsetAsync(deg, 0, (size_t)N * 4, stream);
    hipMemsetAsync(cursor, 0, (size_t)N * 4, stream);

    int egrid = (E2 + 255) / 256;
    k_deg<<<egrid, 256, 0, stream>>>(ei, E, E2, deg);
    int nb = (N + 255) / 256;
    k_scan_block<<<nb, 256, 0, stream>>>(deg, incl, bsum, N);
    k_scan_bsum<<<1, 256, 0, stream>>>(bsum, nb);
    k_rowptr<<<nb, 256, 0, stream>>>(incl, deg, bsum, row_ptr, N, E2);
    k_scatter<<<egrid, 256, 0, stream>>>(ei, E, E2, row_ptr, cursor, csr_src);

    int agrid = (N + 3) / 4;   // 4 waves (nodes) per 256-thread block
    for (int l = 0; l < 5; ++l) {
        const float* W   = (const float*)d_in[2 + 4 * l];
        const float* as_ = (const float*)d_in[3 + 4 * l];
        const float* ad_ = (const float*)d_in[4 + 4 * l];
        const float* bs_ = (const float*)d_in[5 + 4 * l];

        dim3 gg((N + 63) / 64, D / 64);
        const float* xin = (l == 0) ? x : outbuf;
        if (l == 0) k_gemm<128><<<gg, 256, 0, stream>>>(xin, W, as_, ad_, bufH, alpha_src, alpha_dst, N);
        else        k_gemm<256><<<gg, 256, 0, stream>>>(xin, W, as_, ad_, bufH, alpha_src, alpha_dst, N);

        int relu = (l < 4) ? 1 : 0;
        k_aggregate<<<agrid, 256, 0, stream>>>(bufH, row_ptr, csr_src,
                                               alpha_src, alpha_dst, bs_,
                                               outbuf, relu, N);
    }
}

// Round 5
// 666.035 us; speedup vs baseline: 2.6578x; 1.4308x over previous
//
#include <hip/hip_runtime.h>
#include <hip/hip_bf16.h>

#define H 4
#define C 64
#define D 256
#define NEG_SLOPE 0.2f

typedef __attribute__((ext_vector_type(8))) short short8;
typedef __attribute__((ext_vector_type(4))) float f32x4;

static __device__ __forceinline__ unsigned short f2bf_bits(float f) {
    __hip_bfloat16 b = __float2bfloat16(f);
    return __builtin_bit_cast(unsigned short, b);
}
static __device__ __forceinline__ float bf_bits2f(unsigned short u) {
    __hip_bfloat16 b = __builtin_bit_cast(__hip_bfloat16, u);
    return __bfloat162float(b);
}

// ---------------- split f32 -> bf16 hi + bf16 residual ----------------
__global__ void k_split(const float* __restrict__ in, unsigned short* __restrict__ hi,
                        unsigned short* __restrict__ lo, int n4) {
    int i = blockIdx.x * blockDim.x + threadIdx.x;
    if (i >= n4) return;
    float4 v = ((const float4*)in)[i];
    float f[4] = {v.x, v.y, v.z, v.w};
    ushort4 hh, ll;
    unsigned short* hp = &hh.x;
    unsigned short* lp = &ll.x;
    #pragma unroll
    for (int j = 0; j < 4; ++j) {
        unsigned short hb = f2bf_bits(f[j]);
        hp[j] = hb;
        lp[j] = f2bf_bits(f[j] - bf_bits2f(hb));
    }
    ((ushort4*)hi)[i] = hh;
    ((ushort4*)lo)[i] = ll;
}

// ---- MFMA GEMM: h[N,256] = x[N,K] @ W[256,K]^T  (split-bf16, 3 products) ----
// grid = ceil(N/64) blocks x 256 thr (4 waves). Wave w: rows w*16..w*16+15,
// all 256 cols (16 frag accs). Fused alpha_src/dst epilogue (all 4 heads).
template<int K>
__global__ __launch_bounds__(256) void k_gemm_mfma(
        const unsigned short* __restrict__ xh, const unsigned short* __restrict__ xl,
        const unsigned short* __restrict__ wh, const unsigned short* __restrict__ wl,
        const float* __restrict__ att_src, const float* __restrict__ att_dst,
        float* __restrict__ hmat, float* __restrict__ alpha_src,
        float* __restrict__ alpha_dst, int nrows) {
    __shared__ unsigned short sxh[64][40], sxl[64][40];    // pad to 40 (80B rows)
    __shared__ unsigned short swh[256][40], swl[256][40];
    int t = threadIdx.x;
    int w = t >> 6, l = t & 63;
    int r = l & 15, q = l >> 4;
    int row0 = blockIdx.x * 64;
    f32x4 acc[16];
    #pragma unroll
    for (int cf = 0; cf < 16; ++cf) acc[cf] = (f32x4){0.f, 0.f, 0.f, 0.f};

    int srow  = t >> 2;        // staging row 0..63
    int sslot = t & 3;         // 8-elem k-slot 0..3

    for (int k0 = 0; k0 < K; k0 += 32) {
        __syncthreads();
        // stage x tile (64 x 32, hi+lo)
        {
            int gr = row0 + srow;
            uint4 vh = make_uint4(0, 0, 0, 0), vl = make_uint4(0, 0, 0, 0);
            if (gr < nrows) {
                vh = *(const uint4*)&xh[(size_t)gr * K + k0 + sslot * 8];
                vl = *(const uint4*)&xl[(size_t)gr * K + k0 + sslot * 8];
            }
            *(uint4*)&sxh[srow][sslot * 8] = vh;
            *(uint4*)&sxl[srow][sslot * 8] = vl;
        }
        // stage W tile (256 x 32, hi+lo)
        #pragma unroll
        for (int i = 0; i < 4; ++i) {
            int wr = srow + i * 64;
            uint4 vh = *(const uint4*)&wh[(size_t)wr * K + k0 + sslot * 8];
            uint4 vl = *(const uint4*)&wl[(size_t)wr * K + k0 + sslot * 8];
            *(uint4*)&swh[wr][sslot * 8] = vh;
            *(uint4*)&swl[wr][sslot * 8] = vl;
        }
        __syncthreads();
        short8 ah = *(short8*)&sxh[w * 16 + r][q * 8];
        short8 al = *(short8*)&sxl[w * 16 + r][q * 8];
        #pragma unroll
        for (int cf = 0; cf < 16; ++cf) {
            short8 bh = *(short8*)&swh[cf * 16 + r][q * 8];
            short8 bl = *(short8*)&swl[cf * 16 + r][q * 8];
            acc[cf] = __builtin_amdgcn_mfma_f32_16x16x32_bf16(ah, bh, acc[cf], 0, 0, 0);
            acc[cf] = __builtin_amdgcn_mfma_f32_16x16x32_bf16(ah, bl, acc[cf], 0, 0, 0);
            acc[cf] = __builtin_amdgcn_mfma_f32_16x16x32_bf16(al, bh, acc[cf], 0, 0, 0);
        }
    }
    // store h: D[row=(q*4+i)][col=cf*16+r]  (m89 C/D mapping)
    #pragma unroll
    for (int cf = 0; cf < 16; ++cf) {
        #pragma unroll
        for (int i = 0; i < 4; ++i) {
            int gr = row0 + w * 16 + q * 4 + i;
            if (gr < nrows) hmat[(size_t)gr * D + cf * 16 + r] = acc[cf][i];
        }
    }
    // fused alpha epilogue: per head h4, per row, dot over that head's 64 cols
    float asv[16], adv[16];
    #pragma unroll
    for (int cf = 0; cf < 16; ++cf) {
        asv[cf] = att_src[cf * 16 + r];
        adv[cf] = att_dst[cf * 16 + r];
    }
    #pragma unroll
    for (int i = 0; i < 4; ++i) {
        #pragma unroll
        for (int h4 = 0; h4 < 4; ++h4) {
            float ps = 0.f, pd = 0.f;
            #pragma unroll
            for (int j = 0; j < 4; ++j) {
                int cf = h4 * 4 + j;
                ps += acc[cf][i] * asv[cf];
                pd += acc[cf][i] * adv[cf];
            }
            #pragma unroll
            for (int m = 1; m < 16; m <<= 1) {
                ps += __shfl_xor(ps, m);
                pd += __shfl_xor(pd, m);
            }
            int gr = row0 + w * 16 + q * 4 + i;
            if (r == 0 && gr < nrows) {
                alpha_src[gr * H + h4] = ps;
                alpha_dst[gr * H + h4] = pd;
            }
        }
    }
}

// ---------------- CSR build (graph constant across layers) ----------------
__global__ void k_deg(const int* __restrict__ ei, int E, int E2, int* __restrict__ deg) {
    int e = blockIdx.x * blockDim.x + threadIdx.x;
    if (e >= E2) return;
    int de = (e < E) ? ei[E + e] : (e - E);
    atomicAdd(&deg[de], 1);
}

__global__ void k_scan_block(const int* __restrict__ deg, int* __restrict__ incl,
                             int* __restrict__ bsum, int n) {
    __shared__ int sd[256];
    int t = threadIdx.x;
    int i = blockIdx.x * 256 + t;
    int v = (i < n) ? deg[i] : 0;
    sd[t] = v;
    __syncthreads();
    for (int off = 1; off < 256; off <<= 1) {
        int add = (t >= off) ? sd[t - off] : 0;
        __syncthreads();
        sd[t] += add;
        __syncthreads();
    }
    if (i < n) incl[i] = sd[t];
    if (t == 255) bsum[blockIdx.x] = sd[255];
}

__global__ void k_scan_bsum(int* __restrict__ bsum, int nb) {
    __shared__ int sd[256];
    int t = threadIdx.x;
    int v = (t < nb) ? bsum[t] : 0;
    sd[t] = v;
    __syncthreads();
    for (int off = 1; off < 256; off <<= 1) {
        int add = (t >= off) ? sd[t - off] : 0;
        __syncthreads();
        sd[t] += add;
        __syncthreads();
    }
    if (t < nb) bsum[t] = sd[t] - v;  // exclusive block offsets
}

__global__ void k_rowptr(const int* __restrict__ incl, const int* __restrict__ deg,
                         const int* __restrict__ boff, int* __restrict__ row_ptr,
                         int n, int total) {
    int i = blockIdx.x * blockDim.x + threadIdx.x;
    if (i < n) row_ptr[i] = incl[i] - deg[i] + boff[i >> 8];
    if (i == 0) row_ptr[n] = total;
}

__global__ void k_scatter(const int* __restrict__ ei, int E, int E2,
                          const int* __restrict__ row_ptr, int* __restrict__ cursor,
                          int* __restrict__ csr_src) {
    int e = blockIdx.x * blockDim.x + threadIdx.x;
    if (e >= E2) return;
    int se, de;
    if (e < E) { se = ei[e]; de = ei[E + e]; }
    else       { se = e - E; de = se; }
    int pos = atomicAdd(&cursor[de], 1);
    csr_src[row_ptr[de] + pos] = se;
}

// ---- aggregation: wave per node; softmax fused; epilogue splits for next layer ----
__global__ __launch_bounds__(256) void k_aggregate(const float* __restrict__ hmat,
        const int* __restrict__ row_ptr, const int* __restrict__ csr_src,
        const float* __restrict__ alpha_src, const float* __restrict__ alpha_dst,
        const float* __restrict__ bias, float* __restrict__ out_f32,
        unsigned short* __restrict__ outh, unsigned short* __restrict__ outl,
        int relu, int nrows) {
    int node = (blockIdx.x * 256 + threadIdx.x) >> 6;   // wave id == node
    if (node >= nrows) return;
    int lane = threadIdx.x & 63;
    int hh   = lane >> 4;         // head (16 lanes per head)
    int c4   = lane * 4;          // 4 consecutive channels per lane
    int start = row_ptr[node], end = row_ptr[node + 1];
    float a_d = alpha_dst[node * H + hh];
    float4 acc = make_float4(0.f, 0.f, 0.f, 0.f);
    float ssum = 0.f;
    int i = start;
    for (; i + 8 <= end; i += 8) {
        int sn[8];
        #pragma unroll
        for (int j = 0; j < 8; ++j) sn[j] = csr_src[i + j];
        float4 hv[8];
        #pragma unroll
        for (int j = 0; j < 8; ++j)
            hv[j] = *(const float4*)&hmat[(size_t)sn[j] * D + c4];
        float as[8];
        #pragma unroll
        for (int j = 0; j < 8; ++j) as[j] = alpha_src[sn[j] * H + hh];
        #pragma unroll
        for (int j = 0; j < 8; ++j) {
            float a = as[j] + a_d;
            a = a > 0.f ? a : NEG_SLOPE * a;
            float ex = __expf(a);
            ssum += ex;
            acc.x += ex * hv[j].x; acc.y += ex * hv[j].y;
            acc.z += ex * hv[j].z; acc.w += ex * hv[j].w;
        }
    }
    for (; i < end; ++i) {
        int sn = csr_src[i];
        float4 hv = *(const float4*)&hmat[(size_t)sn * D + c4];
        float a = alpha_src[sn * H + hh] + a_d;
        a = a > 0.f ? a : NEG_SLOPE * a;
        float ex = __expf(a);
        ssum += ex;
        acc.x += ex * hv.x; acc.y += ex * hv.y; acc.z += ex * hv.z; acc.w += ex * hv.w;
    }
    float sinv = 1.f / (ssum + 1e-16f);
    float4 bv = *(const float4*)&bias[c4];
    float o[4];
    o[0] = acc.x * sinv + bv.x;
    o[1] = acc.y * sinv + bv.y;
    o[2] = acc.z * sinv + bv.z;
    o[3] = acc.w * sinv + bv.w;
    if (relu) {
        #pragma unroll
        for (int j = 0; j < 4; ++j) o[j] = fmaxf(o[j], 0.f);
    }
    if (outh) {
        ushort4 hh4, ll4;
        unsigned short* hp = &hh4.x;
        unsigned short* lp = &ll4.x;
        #pragma unroll
        for (int j = 0; j < 4; ++j) {
            unsigned short hb = f2bf_bits(o[j]);
            hp[j] = hb;
            lp[j] = f2bf_bits(o[j] - bf_bits2f(hb));
        }
        *(ushort4*)&outh[(size_t)node * D + c4] = hh4;
        *(ushort4*)&outl[(size_t)node * D + c4] = ll4;
    } else {
        *(float4*)&out_f32[(size_t)node * D + c4] =
            make_float4(o[0], o[1], o[2], o[3]);
    }
}

extern "C" void kernel_launch(void* const* d_in, const int* in_sizes, int n_in,
                              void* d_out, int out_size, void* d_ws, size_t ws_size,
                              hipStream_t stream) {
    const float* x = (const float*)d_in[0];
    const int* ei = (const int*)d_in[1];
    const int N  = in_sizes[0] / 128;   // 50000
    const int E  = in_sizes[1] / 2;     // 400000
    const int E2 = E + N;               // + self loops

    char* wsp = (char*)d_ws;
    size_t off = 0;
    auto alloc = [&](size_t bytes) -> void* {
        void* p = wsp + off;
        off += (bytes + 255) & ~(size_t)255;
        return p;
    };
    float*          bufH      = (float*)alloc((size_t)N * D * 4);           // 51.2 MB
    unsigned short* xhi       = (unsigned short*)alloc((size_t)N * D * 2);  // 25.6 MB
    unsigned short* xlo       = (unsigned short*)alloc((size_t)N * D * 2);  // 25.6 MB
    unsigned short* whi       = (unsigned short*)alloc((size_t)5 * D * D * 2);
    unsigned short* wlo       = (unsigned short*)alloc((size_t)5 * D * D * 2);
    float* alpha_src = (float*)alloc((size_t)N * H * 4);
    float* alpha_dst = (float*)alloc((size_t)N * H * 4);
    int*   deg       = (int*)alloc((size_t)N * 4);
    int*   incl      = (int*)alloc((size_t)N * 4);
    int*   bsum      = (int*)alloc(256 * 4);
    int*   row_ptr   = (int*)alloc((size_t)(N + 1) * 4);
    int*   cursor    = (int*)alloc((size_t)N * 4);
    int*   csr_src   = (int*)alloc((size_t)E2 * 4);
    (void)ws_size;

    hipMemsetAsync(deg, 0, (size_t)N * 4, stream);
    hipMemsetAsync(cursor, 0, (size_t)N * 4, stream);

    // split x (N x 128) and all 5 W matrices into bf16 hi/lo
    int nx4 = N * 128 / 4;
    k_split<<<(nx4 + 255) / 256, 256, 0, stream>>>(x, xhi, xlo, nx4);
    for (int l = 0; l < 5; ++l) {
        const float* W = (const float*)d_in[2 + 4 * l];
        int nw4 = D * (l == 0 ? 128 : 256) / 4;
        k_split<<<(nw4 + 255) / 256, 256, 0, stream>>>(W, whi + (size_t)l * D * D,
                                                       wlo + (size_t)l * D * D, nw4);
    }

    // CSR by dst
    int egrid = (E2 + 255) / 256;
    k_deg<<<egrid, 256, 0, stream>>>(ei, E, E2, deg);
    int nb = (N + 255) / 256;
    k_scan_block<<<nb, 256, 0, stream>>>(deg, incl, bsum, N);
    k_scan_bsum<<<1, 256, 0, stream>>>(bsum, nb);
    k_rowptr<<<nb, 256, 0, stream>>>(incl, deg, bsum, row_ptr, N, E2);
    k_scatter<<<egrid, 256, 0, stream>>>(ei, E, E2, row_ptr, cursor, csr_src);

    int ggrid = (N + 63) / 64;
    int agrid = (N + 3) / 4;
    for (int l = 0; l < 5; ++l) {
        const float* as_ = (const float*)d_in[3 + 4 * l];
        const float* ad_ = (const float*)d_in[4 + 4 * l];
        const float* bs_ = (const float*)d_in[5 + 4 * l];
        const unsigned short* wh = whi + (size_t)l * D * D;
        const unsigned short* wl = wlo + (size_t)l * D * D;

        if (l == 0)
            k_gemm_mfma<128><<<ggrid, 256, 0, stream>>>(xhi, xlo, wh, wl, as_, ad_,
                                                        bufH, alpha_src, alpha_dst, N);
        else
            k_gemm_mfma<256><<<ggrid, 256, 0, stream>>>(xhi, xlo, wh, wl, as_, ad_,
                                                        bufH, alpha_src, alpha_dst, N);

        int last = (l == 4);
        k_aggregate<<<agrid, 256, 0, stream>>>(bufH, row_ptr, csr_src,
                                               alpha_src, alpha_dst, bs_,
                                               last ? (float*)d_out : nullptr,
                                               last ? nullptr : xhi,
                                               last ? nullptr : xlo,
                                               last ? 0 : 1, N);
    }
}

// Round 6
// 460.013 us; speedup vs baseline: 3.8482x; 1.4479x over previous
//
#include <hip/hip_runtime.h>
#include <hip/hip_bf16.h>

#define H 4
#define C 64
#define D 256
#define NEG_SLOPE 0.2f

typedef __attribute__((ext_vector_type(8))) _Float16 f16x8;
typedef __attribute__((ext_vector_type(4))) _Float16 f16x4;
typedef __attribute__((ext_vector_type(4))) float f32x4;

// ---------------- f32 -> f16 convert (vector-4) ----------------
__global__ void k_cvt(const float* __restrict__ in, _Float16* __restrict__ out, int n4) {
    int i = blockIdx.x * blockDim.x + threadIdx.x;
    if (i >= n4) return;
    float4 v = ((const float4*)in)[i];
    f16x4 o = {(_Float16)v.x, (_Float16)v.y, (_Float16)v.z, (_Float16)v.w};
    *(f16x4*)&out[(size_t)i * 4] = o;
}

// ---- MFMA GEMM (fp16): h[N,256] = x[N,K] @ W[256,K]^T, fused alpha ----
// grid = ceil(N/64) x 256thr (4 waves). Wave w: rows w*16..+15, all 256 cols.
template<int K>
__global__ __launch_bounds__(256) void k_gemm_mfma(
        const _Float16* __restrict__ xf, const _Float16* __restrict__ wf,
        const float* __restrict__ att_src, const float* __restrict__ att_dst,
        _Float16* __restrict__ hmat, float* __restrict__ alpha_src,
        float* __restrict__ alpha_dst, int nrows) {
    __shared__ _Float16 sx[64][40];     // pad 32->40 (80B rows)
    __shared__ _Float16 sw[256][40];
    int t = threadIdx.x;
    int w = t >> 6, l = t & 63;
    int r = l & 15, q = l >> 4;
    int row0 = blockIdx.x * 64;
    f32x4 acc[16];
    #pragma unroll
    for (int cf = 0; cf < 16; ++cf) acc[cf] = (f32x4){0.f, 0.f, 0.f, 0.f};

    int srow  = t >> 2;        // staging row 0..63
    int sslot = t & 3;         // 8-elem k-slot 0..3

    for (int k0 = 0; k0 < K; k0 += 32) {
        __syncthreads();
        {
            int gr = row0 + srow;
            uint4 v = make_uint4(0, 0, 0, 0);
            if (gr < nrows) v = *(const uint4*)&xf[(size_t)gr * K + k0 + sslot * 8];
            *(uint4*)&sx[srow][sslot * 8] = v;
        }
        #pragma unroll
        for (int i = 0; i < 4; ++i) {
            int wr = srow + i * 64;
            uint4 v = *(const uint4*)&wf[(size_t)wr * K + k0 + sslot * 8];
            *(uint4*)&sw[wr][sslot * 8] = v;
        }
        __syncthreads();
        f16x8 a = *(f16x8*)&sx[w * 16 + r][q * 8];
        #pragma unroll
        for (int cf = 0; cf < 16; ++cf) {
            f16x8 b = *(f16x8*)&sw[cf * 16 + r][q * 8];
            acc[cf] = __builtin_amdgcn_mfma_f32_16x16x32_f16(a, b, acc[cf], 0, 0, 0);
        }
    }
    // store h (fp16): D[row=(q*4+i)][col=cf*16+r]
    #pragma unroll
    for (int cf = 0; cf < 16; ++cf) {
        #pragma unroll
        for (int i = 0; i < 4; ++i) {
            int gr = row0 + w * 16 + q * 4 + i;
            if (gr < nrows) hmat[(size_t)gr * D + cf * 16 + r] = (_Float16)acc[cf][i];
        }
    }
    // fused alpha epilogue (f32 accs)
    float asv[16], adv[16];
    #pragma unroll
    for (int cf = 0; cf < 16; ++cf) {
        asv[cf] = att_src[cf * 16 + r];
        adv[cf] = att_dst[cf * 16 + r];
    }
    #pragma unroll
    for (int i = 0; i < 4; ++i) {
        #pragma unroll
        for (int h4 = 0; h4 < 4; ++h4) {
            float ps = 0.f, pd = 0.f;
            #pragma unroll
            for (int j = 0; j < 4; ++j) {
                int cf = h4 * 4 + j;
                ps += acc[cf][i] * asv[cf];
                pd += acc[cf][i] * adv[cf];
            }
            #pragma unroll
            for (int m = 1; m < 16; m <<= 1) {
                ps += __shfl_xor(ps, m);
                pd += __shfl_xor(pd, m);
            }
            int gr = row0 + w * 16 + q * 4 + i;
            if (r == 0 && gr < nrows) {
                alpha_src[gr * H + h4] = ps;
                alpha_dst[gr * H + h4] = pd;
            }
        }
    }
}

// ---------------- CSR build (graph constant across layers) ----------------
__global__ void k_deg(const int* __restrict__ ei, int E, int E2, int* __restrict__ deg) {
    int e = blockIdx.x * blockDim.x + threadIdx.x;
    if (e >= E2) return;
    int de = (e < E) ? ei[E + e] : (e - E);
    atomicAdd(&deg[de], 1);
}

__global__ void k_scan_block(const int* __restrict__ deg, int* __restrict__ incl,
                             int* __restrict__ bsum, int n) {
    __shared__ int sd[256];
    int t = threadIdx.x;
    int i = blockIdx.x * 256 + t;
    int v = (i < n) ? deg[i] : 0;
    sd[t] = v;
    __syncthreads();
    for (int off = 1; off < 256; off <<= 1) {
        int add = (t >= off) ? sd[t - off] : 0;
        __syncthreads();
        sd[t] += add;
        __syncthreads();
    }
    if (i < n) incl[i] = sd[t];
    if (t == 255) bsum[blockIdx.x] = sd[255];
}

__global__ void k_scan_bsum(int* __restrict__ bsum, int nb) {
    __shared__ int sd[256];
    int t = threadIdx.x;
    int v = (t < nb) ? bsum[t] : 0;
    sd[t] = v;
    __syncthreads();
    for (int off = 1; off < 256; off <<= 1) {
        int add = (t >= off) ? sd[t - off] : 0;
        __syncthreads();
        sd[t] += add;
        __syncthreads();
    }
    if (t < nb) bsum[t] = sd[t] - v;  // exclusive block offsets
}

__global__ void k_rowptr(const int* __restrict__ incl, const int* __restrict__ deg,
                         const int* __restrict__ boff, int* __restrict__ row_ptr,
                         int n, int total) {
    int i = blockIdx.x * blockDim.x + threadIdx.x;
    if (i < n) row_ptr[i] = incl[i] - deg[i] + boff[i >> 8];
    if (i == 0) row_ptr[n] = total;
}

__global__ void k_scatter(const int* __restrict__ ei, int E, int E2,
                          const int* __restrict__ row_ptr, int* __restrict__ cursor,
                          int* __restrict__ csr_src) {
    int e = blockIdx.x * blockDim.x + threadIdx.x;
    if (e >= E2) return;
    int se, de;
    if (e < E) { se = ei[e]; de = ei[E + e]; }
    else       { se = e - E; de = se; }
    int pos = atomicAdd(&cursor[de], 1);
    csr_src[row_ptr[de] + pos] = se;
}

// ---- aggregation: wave per node; softmax fused; fp16 gather; fp16 x out ----
__global__ __launch_bounds__(256) void k_aggregate(const _Float16* __restrict__ hmat,
        const int* __restrict__ row_ptr, const int* __restrict__ csr_src,
        const float* __restrict__ alpha_src, const float* __restrict__ alpha_dst,
        const float* __restrict__ bias, float* __restrict__ out_f32,
        _Float16* __restrict__ outx, int relu, int nrows) {
    int node = (blockIdx.x * 256 + threadIdx.x) >> 6;   // wave id == node
    if (node >= nrows) return;
    int lane = threadIdx.x & 63;
    int hh   = lane >> 4;         // head (16 lanes per head)
    int c4   = lane * 4;          // 4 consecutive channels per lane
    int start = row_ptr[node], end = row_ptr[node + 1];
    float a_d = alpha_dst[node * H + hh];
    float4 acc = make_float4(0.f, 0.f, 0.f, 0.f);
    float ssum = 0.f;
    int i = start;
    for (; i + 8 <= end; i += 8) {
        int sn[8];
        #pragma unroll
        for (int j = 0; j < 8; ++j) sn[j] = csr_src[i + j];
        f16x4 hv[8];
        #pragma unroll
        for (int j = 0; j < 8; ++j)
            hv[j] = *(const f16x4*)&hmat[(size_t)sn[j] * D + c4];
        float as[8];
        #pragma unroll
        for (int j = 0; j < 8; ++j) as[j] = alpha_src[sn[j] * H + hh];
        #pragma unroll
        for (int j = 0; j < 8; ++j) {
            float a = as[j] + a_d;
            a = a > 0.f ? a : NEG_SLOPE * a;
            float ex = __expf(a);
            ssum += ex;
            acc.x += ex * (float)hv[j][0]; acc.y += ex * (float)hv[j][1];
            acc.z += ex * (float)hv[j][2]; acc.w += ex * (float)hv[j][3];
        }
    }
    for (; i < end; ++i) {
        int sn = csr_src[i];
        f16x4 hv = *(const f16x4*)&hmat[(size_t)sn * D + c4];
        float a = alpha_src[sn * H + hh] + a_d;
        a = a > 0.f ? a : NEG_SLOPE * a;
        float ex = __expf(a);
        ssum += ex;
        acc.x += ex * (float)hv[0]; acc.y += ex * (float)hv[1];
        acc.z += ex * (float)hv[2]; acc.w += ex * (float)hv[3];
    }
    float sinv = 1.f / (ssum + 1e-16f);
    float4 bv = *(const float4*)&bias[c4];
    float o[4];
    o[0] = acc.x * sinv + bv.x;
    o[1] = acc.y * sinv + bv.y;
    o[2] = acc.z * sinv + bv.z;
    o[3] = acc.w * sinv + bv.w;
    if (relu) {
        #pragma unroll
        for (int j = 0; j < 4; ++j) o[j] = fmaxf(o[j], 0.f);
    }
    if (outx) {
        f16x4 o4 = {(_Float16)o[0], (_Float16)o[1], (_Float16)o[2], (_Float16)o[3]};
        *(f16x4*)&outx[(size_t)node * D + c4] = o4;
    } else {
        *(float4*)&out_f32[(size_t)node * D + c4] =
            make_float4(o[0], o[1], o[2], o[3]);
    }
}

extern "C" void kernel_launch(void* const* d_in, const int* in_sizes, int n_in,
                              void* d_out, int out_size, void* d_ws, size_t ws_size,
                              hipStream_t stream) {
    const float* x = (const float*)d_in[0];
    const int* ei = (const int*)d_in[1];
    const int N  = in_sizes[0] / 128;   // 50000
    const int E  = in_sizes[1] / 2;     // 400000
    const int E2 = E + N;               // + self loops

    char* wsp = (char*)d_ws;
    size_t off = 0;
    auto alloc = [&](size_t bytes) -> void* {
        void* p = wsp + off;
        off += (bytes + 255) & ~(size_t)255;
        return p;
    };
    _Float16* bufH  = (_Float16*)alloc((size_t)N * D * 2);     // 25.6 MB
    _Float16* xf16  = (_Float16*)alloc((size_t)N * D * 2);     // 25.6 MB
    _Float16* wf16  = (_Float16*)alloc((size_t)5 * D * D * 2); // 0.66 MB
    float* alpha_src = (float*)alloc((size_t)N * H * 4);
    float* alpha_dst = (float*)alloc((size_t)N * H * 4);
    int*   deg       = (int*)alloc((size_t)N * 4);
    int*   incl      = (int*)alloc((size_t)N * 4);
    int*   bsum      = (int*)alloc(256 * 4);
    int*   row_ptr   = (int*)alloc((size_t)(N + 1) * 4);
    int*   cursor    = (int*)alloc((size_t)N * 4);
    int*   csr_src   = (int*)alloc((size_t)E2 * 4);
    (void)ws_size;

    hipMemsetAsync(deg, 0, (size_t)N * 4, stream);
    hipMemsetAsync(cursor, 0, (size_t)N * 4, stream);

    // convert x (N x 128) and all 5 W matrices to fp16
    int nx4 = N * 128 / 4;
    k_cvt<<<(nx4 + 255) / 256, 256, 0, stream>>>(x, xf16, nx4);
    for (int l = 0; l < 5; ++l) {
        const float* W = (const float*)d_in[2 + 4 * l];
        int nw4 = D * (l == 0 ? 128 : 256) / 4;
        k_cvt<<<(nw4 + 255) / 256, 256, 0, stream>>>(W, wf16 + (size_t)l * D * D, nw4);
    }

    // CSR by dst
    int egrid = (E2 + 255) / 256;
    k_deg<<<egrid, 256, 0, stream>>>(ei, E, E2, deg);
    int nb = (N + 255) / 256;
    k_scan_block<<<nb, 256, 0, stream>>>(deg, incl, bsum, N);
    k_scan_bsum<<<1, 256, 0, stream>>>(bsum, nb);
    k_rowptr<<<nb, 256, 0, stream>>>(incl, deg, bsum, row_ptr, N, E2);
    k_scatter<<<egrid, 256, 0, stream>>>(ei, E, E2, row_ptr, cursor, csr_src);

    int ggrid = (N + 63) / 64;
    int agrid = (N + 3) / 4;
    for (int l = 0; l < 5; ++l) {
        const float* as_ = (const float*)d_in[3 + 4 * l];
        const float* ad_ = (const float*)d_in[4 + 4 * l];
        const float* bs_ = (const float*)d_in[5 + 4 * l];
        const _Float16* wl = wf16 + (size_t)l * D * D;

        if (l == 0)
            k_gemm_mfma<128><<<ggrid, 256, 0, stream>>>(xf16, wl, as_, ad_,
                                                        bufH, alpha_src, alpha_dst, N);
        else
            k_gemm_mfma<256><<<ggrid, 256, 0, stream>>>(xf16, wl, as_, ad_,
                                                        bufH, alpha_src, alpha_dst, N);

        int last = (l == 4);
        k_aggregate<<<agrid, 256, 0, stream>>>(bufH, row_ptr, csr_src,
                                               alpha_src, alpha_dst, bs_,
                                               last ? (float*)d_out : nullptr,
                                               last ? nullptr : xf16,
                                               last ? 0 : 1, N);
    }
}